// Round 2
// baseline (742.950 us; speedup 1.0000x reference)
//
#include <hip/hip_runtime.h>
#include <stdint.h>

#define N_NODES 50000
#define N_EDGES 1600000
#define F_IN    264
#define F_HID   48
#define F_CAT   144
#define F_MID   64
#define K_PAD   288   // 264 padded up to multiple of 32

typedef unsigned short u16;
typedef unsigned int   u32;

using short8  = __attribute__((ext_vector_type(8))) short;
using floatx4 = __attribute__((ext_vector_type(4))) float;

__device__ __forceinline__ float bf2f(u16 u) {
    return __uint_as_float(((u32)u) << 16);
}
__device__ __forceinline__ u16 f2bf(float f) {
    u32 u = __float_as_uint(f);
    u32 r = (u + 0x7fffu + ((u >> 16) & 1u)) >> 16;   // round-nearest-even
    return (u16)r;
}
// dtype-agnostic scalar float load: isbf ? bf16[i] : f32[i]
__device__ __forceinline__ float ldf(const void* p, size_t i, int isbf) {
    return isbf ? bf2f(((const u16*)p)[i]) : ((const float*)p)[i];
}
__device__ __forceinline__ floatx4 max4(floatx4 a, floatx4 b) {
    floatx4 r;
    r[0] = fmaxf(a[0], b[0]); r[1] = fmaxf(a[1], b[1]);
    r[2] = fmaxf(a[2], b[2]); r[3] = fmaxf(a[3], b[3]);
    return r;
}

// ---------- dtype probe: flags[0]=floats-are-bf16, flags[1]=ints-are-int64 ----
__global__ __launch_bounds__(64)
void k_probe(const u16* __restrict__ xu, const int* __restrict__ ei,
             int* __restrict__ flags) {
    int lane = threadIdx.x;
    // float probe: even u16s are genuine bf16 iff storage is bf16
    u16 h = xu[2 * lane];
    u32 E = (h >> 7) & 0xFF;
    int sane = (h == 0) || (E >= 90 && E <= 140);
    unsigned long long m = __ballot(sane);
    int cnt = __popcll(m);
    // int probe: odd words all zero iff storage is int64 (values < 2^31)
    int z = (lane < 16) ? ei[2 * lane + 1] : 0;
    unsigned long long nz = __ballot(z != 0);
    if (lane == 0) {
        flags[0] = (cnt >= 48) ? 1 : 0;
        flags[1] = (nz == 0ull) ? 1 : 0;
    }
}

__device__ __forceinline__ int ld_row(const int* ei, int e, int is64) {
    return is64 ? ei[2 * (size_t)e] : ei[e];
}
__device__ __forceinline__ int ld_col(const int* ei, int e, int is64) {
    return is64 ? ei[2 * ((size_t)N_EDGES + e)] : ei[(size_t)N_EDGES + e];
}

// ---------- weight staging: Wt[n][k] transposed, bf16, zero-padded to K_PAD ----
__global__ __launch_bounds__(256)
void k_prepWt(const void* __restrict__ WM, const void* __restrict__ WA,
              const void* __restrict__ WS, u16* __restrict__ Wt,
              const int* __restrict__ flags) {
    const int isbf = flags[0];
    int t = blockIdx.x * 256 + threadIdx.x;
    if (t >= F_CAT * K_PAD) return;
    int n = t / K_PAD, k = t - n * K_PAD;
    u16 v = 0;
    if (k < F_IN) {
        const void* W = (n < 48) ? WM : (n < 96) ? WA : WS;
        int nn = (n < 48) ? n : (n < 96) ? n - 48 : n - 96;
        if (isbf) v = ((const u16*)W)[(size_t)k * 48 + nn];
        else      v = f2bf(((const float*)W)[(size_t)k * 48 + nn]);
    }
    Wt[(size_t)n * K_PAD + k] = v;
}

__global__ __launch_bounds__(256)
void k_init(float* __restrict__ deg, int* __restrict__ count) {
    int i = blockIdx.x * 256 + threadIdx.x;
    if (i < N_NODES) { deg[i] = 1.0f; count[i] = 0; }  // self-loop weight 1
}

__global__ __launch_bounds__(256)
void k_epass1(const int* __restrict__ ei, const void* __restrict__ ew,
              float* __restrict__ deg, int* __restrict__ count,
              const int* __restrict__ flags) {
    const int isbf = flags[0], is64 = flags[1];
    int e = blockIdx.x * 256 + threadIdx.x;
    if (e >= N_EDGES) return;
    int c = ld_col(ei, e, is64);
    atomicAdd(&deg[c], ldf(ew, e, isbf));
    atomicAdd(&count[c], 1);
}

__global__ __launch_bounds__(256)
void k_dis(const float* __restrict__ deg, float* __restrict__ dis) {
    int i = blockIdx.x * 256 + threadIdx.x;
    if (i < N_NODES) dis[i] = rsqrtf(deg[i]);   // deg >= 1 always
}

__global__ __launch_bounds__(1024)
void k_scan(const int* __restrict__ count, int* __restrict__ rowptr,
            int* __restrict__ cursor) {
    __shared__ int part[1024];
    const int tid = threadIdx.x;
    const int CH = (N_NODES + 1023) / 1024;  // 49
    int base = tid * CH;
    int lim = base + CH; if (lim > N_NODES) lim = N_NODES;
    int s = 0;
    for (int i = base; i < lim; ++i) s += count[i];
    part[tid] = s;
    __syncthreads();
    for (int off = 1; off < 1024; off <<= 1) {
        int v = (tid >= off) ? part[tid - off] : 0;
        __syncthreads();
        part[tid] += v;
        __syncthreads();
    }
    int run = part[tid] - s;     // exclusive prefix
    for (int i = base; i < lim; ++i) {
        rowptr[i] = run; cursor[i] = run; run += count[i];
    }
    if (tid == 1023) rowptr[N_NODES] = part[1023];
}

__global__ __launch_bounds__(256)
void k_epass2(const int* __restrict__ ei, const void* __restrict__ ew,
              const float* __restrict__ dis, int* __restrict__ cursor,
              int* __restrict__ csr_src, float* __restrict__ csr_w,
              const int* __restrict__ flags) {
    const int isbf = flags[0], is64 = flags[1];
    int e = blockIdx.x * 256 + threadIdx.x;
    if (e >= N_EDGES) return;
    int r = ld_row(ei, e, is64);
    int c = ld_col(ei, e, is64);
    float nm = dis[r] * ldf(ew, e, isbf) * dis[c];
    int p = atomicAdd(&cursor[c], 1);
    csr_src[p] = r;
    csr_w[p] = nm;
}

// ---------- GEMM: H[50000 x 144] = x @ [WM|WA|WS] via bf16 MFMA ----------
// outputs: hMA[node][96] fp32 (raw hM|hA, no bias), xLin[node][48] = relu(.+bS)
__global__ __launch_bounds__(256)
void k_gemm(const void* __restrict__ x, const u16* __restrict__ Wt,
            const void* __restrict__ bS, float* __restrict__ hMA,
            float* __restrict__ xLin, const int* __restrict__ flags) {
    const int isbf = flags[0];
    const int lane = threadIdx.x & 63;
    const int wave = threadIdx.x >> 6;
    const int mrow = lane & 15;
    const int q    = lane >> 4;
    const int m_base = blockIdx.x * 64 + wave * 16;
    const int node = m_base + mrow;

    floatx4 acc[9];
#pragma unroll
    for (int t = 0; t < 9; ++t) { acc[t][0]=0.f; acc[t][1]=0.f; acc[t][2]=0.f; acc[t][3]=0.f; }

    for (int k0 = 0; k0 < K_PAD; k0 += 32) {
        int k = k0 + q * 8;
        short8 a = {0,0,0,0,0,0,0,0};
        if (node < N_NODES && k < F_IN) {
            if (isbf) {
                a = *(const short8*)((const u16*)x + (size_t)node * F_IN + k);
            } else {
                const float* xf = (const float*)x + (size_t)node * F_IN + k;
                floatx4 v0 = *(const floatx4*)xf;
                floatx4 v1 = *(const floatx4*)(xf + 4);
                a[0]=(short)f2bf(v0[0]); a[1]=(short)f2bf(v0[1]);
                a[2]=(short)f2bf(v0[2]); a[3]=(short)f2bf(v0[3]);
                a[4]=(short)f2bf(v1[0]); a[5]=(short)f2bf(v1[1]);
                a[6]=(short)f2bf(v1[2]); a[7]=(short)f2bf(v1[3]);
            }
        }
#pragma unroll
        for (int t = 0; t < 9; ++t) {
            short8 b = *(const short8*)(Wt + (size_t)(t * 16 + mrow) * K_PAD + k);
            acc[t] = __builtin_amdgcn_mfma_f32_16x16x32_bf16(a, b, acc[t], 0, 0, 0);
        }
    }
#pragma unroll
    for (int t = 0; t < 9; ++t) {
        int n = t * 16 + mrow;                  // C/D col = lane&15
#pragma unroll
        for (int r = 0; r < 4; ++r) {
            int row = m_base + q * 4 + r;       // C/D row = (lane>>4)*4 + reg
            if (row < N_NODES) {
                float v = acc[t][r];
                if (n < 96) hMA[(size_t)row * 96 + n] = v;
                else        xLin[(size_t)row * 48 + (n - 96)] =
                                fmaxf(v + ldf(bS, n - 96, isbf), 0.f);
            }
        }
    }
}

// ---------- fused aggregation + MLP: one wave per node ----------
__global__ __launch_bounds__(256)
void k_agg(const float* __restrict__ hMA, const float* __restrict__ xLin,
           const int* __restrict__ rowptr, const int* __restrict__ csr_src,
           const float* __restrict__ csr_w, const float* __restrict__ dis,
           const void* __restrict__ bM, const void* __restrict__ bA,
           const void* __restrict__ W1, const void* __restrict__ b1,
           const void* __restrict__ W2, const void* __restrict__ b2,
           void* __restrict__ out, const int* __restrict__ flags) {
    __shared__ __align__(16) float hsh[4][F_CAT];
    const int isbf = flags[0];
    const int lane = threadIdx.x & 63;
    const int wave = threadIdx.x >> 6;
    const int node = blockIdx.x * 4 + wave;   // grid = 12500*4 == 50000 exactly

    const int start = rowptr[node];
    const int end   = rowptr[node + 1];
    const bool isMax = lane < 12;             // lanes 0..11: hM (max), 12..23: hA (sum)
    const bool act   = lane < 24;

    floatx4 acc;
    { float init = isMax ? -3.4e38f : 0.f;
      acc[0]=init; acc[1]=init; acc[2]=init; acc[3]=init; }

    const float* tab = hMA + 4 * lane;        // float4 slot within the 96-wide row
    for (int e = start; e < end; ++e) {
        int r = csr_src[e];
        float nm = csr_w[e];
        if (act) {
            floatx4 v = *(const floatx4*)(tab + (size_t)r * 96);
            floatx4 m = nm * v;
            if (isMax) acc = max4(acc, m); else acc += m;
        }
    }
    // self-loop: weight 1 -> norm = dis[node]^2
    {
        float dn = dis[node];
        float sn = dn * dn;
        if (act) {
            floatx4 v = *(const floatx4*)(tab + (size_t)node * 96);
            floatx4 m = sn * v;
            if (isMax) acc = max4(acc, m); else acc += m;
        }
    }
    if (act) {
        floatx4 res;
#pragma unroll
        for (int j = 0; j < 4; ++j) {
            float b = isMax ? ldf(bM, 4 * lane + j, isbf)
                            : ldf(bA, 4 * (lane - 12) + j, isbf);
            res[j] = fmaxf(acc[j] + b, 0.f);
        }
        *(floatx4*)(&hsh[wave][4 * lane]) = res;         // [0,96)
    } else if (lane < 36) {
        *(floatx4*)(&hsh[wave][4 * lane]) =              // [96,144)
            *(const floatx4*)(xLin + (size_t)node * 48 + 4 * (lane - 24));
    }
    __syncthreads();

    // MLP: lane j computes mid[j]
    float mid = ldf(b1, lane, isbf);
    if (isbf) {
        const u16* W1h = (const u16*)W1;
        for (int k = 0; k < F_CAT; ++k)
            mid = fmaf(hsh[wave][k], bf2f(W1h[k * F_MID + lane]), mid);
    } else {
        const float* W1f = (const float*)W1;
        for (int k = 0; k < F_CAT; ++k)
            mid = fmaf(hsh[wave][k], W1f[k * F_MID + lane], mid);
    }
    mid = fmaxf(mid, 0.f);
    float c2 = mid * ldf(W2, lane, isbf);
#pragma unroll
    for (int off = 32; off > 0; off >>= 1) c2 += __shfl_down(c2, off, 64);
    if (lane == 0) {
        float res = c2 + ldf(b2, 0, isbf);
        if (isbf) ((u16*)out)[node] = f2bf(res);
        else      ((float*)out)[node] = res;
    }
}

extern "C" void kernel_launch(void* const* d_in, const int* in_sizes, int n_in,
                              void* d_out, int out_size, void* d_ws, size_t ws_size,
                              hipStream_t stream) {
    const void* x  = d_in[0];
    const int*  ei = (const int*)d_in[1];
    const void* ew = d_in[2];
    const void* WM = d_in[3];
    const void* bM = d_in[4];
    const void* WA = d_in[5];
    const void* bA = d_in[6];
    const void* WS = d_in[7];
    const void* bS = d_in[8];
    const void* W1 = d_in[9];
    const void* b1 = d_in[10];
    const void* W2 = d_in[11];
    const void* b2 = d_in[12];

    char* p = (char*)d_ws;
    auto alloc = [&](size_t bytes) -> char* {
        char* r = p; p += (bytes + 255) & ~(size_t)255; return r;
    };
    int*   flags   = (int*)  alloc(16);
    float* deg     = (float*)alloc((size_t)N_NODES * 4);
    float* dis     = (float*)alloc((size_t)N_NODES * 4);
    int*   count   = (int*)  alloc((size_t)N_NODES * 4);
    int*   rowptr  = (int*)  alloc((size_t)(N_NODES + 1) * 4);
    int*   cursor  = (int*)  alloc((size_t)N_NODES * 4);
    int*   csr_src = (int*)  alloc((size_t)N_EDGES * 4);
    float* csr_w   = (float*)alloc((size_t)N_EDGES * 4);
    float* hMA     = (float*)alloc((size_t)N_NODES * 96 * 4);
    float* xLin    = (float*)alloc((size_t)N_NODES * 48 * 4);
    u16*   Wt      = (u16*)  alloc((size_t)F_CAT * K_PAD * 2);

    k_probe <<<1, 64, 0, stream>>>((const u16*)x, ei, flags);
    k_prepWt<<<(F_CAT * K_PAD + 255) / 256, 256, 0, stream>>>(WM, WA, WS, Wt, flags);
    k_init  <<<(N_NODES + 255) / 256, 256, 0, stream>>>(deg, count);
    k_epass1<<<(N_EDGES + 255) / 256, 256, 0, stream>>>(ei, ew, deg, count, flags);
    k_dis   <<<(N_NODES + 255) / 256, 256, 0, stream>>>(deg, dis);
    k_scan  <<<1, 1024, 0, stream>>>(count, rowptr, cursor);
    k_epass2<<<(N_EDGES + 255) / 256, 256, 0, stream>>>(ei, ew, dis, cursor, csr_src, csr_w, flags);
    k_gemm  <<<(N_NODES + 63) / 64, 256, 0, stream>>>(x, Wt, bS, hMA, xLin, flags);
    k_agg   <<<N_NODES / 4, 256, 0, stream>>>(hMA, xLin, rowptr, csr_src, csr_w, dis,
                                              bM, bA, W1, b1, W2, b2, d_out, flags);
    (void)in_sizes; (void)n_in; (void)out_size; (void)ws_size;
}

// Round 4
// 553.012 us; speedup vs baseline: 1.3435x; 1.3435x over previous
//
#include <hip/hip_runtime.h>
#include <stdint.h>

#define N_NODES 50000
#define N_EDGES 1600000
#define F_IN    264
#define F_HID   48
#define F_CAT   144
#define F_MID   64
#define K_PAD   288   // 264 padded up to multiple of 32

typedef unsigned short u16;
typedef unsigned int   u32;

using short8  = __attribute__((ext_vector_type(8))) short;
using floatx4 = __attribute__((ext_vector_type(4))) float;

__device__ __forceinline__ float bf2f(u16 u) {
    return __uint_as_float(((u32)u) << 16);
}
__device__ __forceinline__ u16 f2bf(float f) {
    u32 u = __float_as_uint(f);
    u32 r = (u + 0x7fffu + ((u >> 16) & 1u)) >> 16;   // round-nearest-even
    return (u16)r;
}
// dtype-agnostic scalar float load: isbf ? bf16[i] : f32[i]
__device__ __forceinline__ float ldf(const void* p, size_t i, int isbf) {
    return isbf ? bf2f(((const u16*)p)[i]) : ((const float*)p)[i];
}
__device__ __forceinline__ floatx4 max4(floatx4 a, floatx4 b) {
    floatx4 r;
    r[0] = fmaxf(a[0], b[0]); r[1] = fmaxf(a[1], b[1]);
    r[2] = fmaxf(a[2], b[2]); r[3] = fmaxf(a[3], b[3]);
    return r;
}

// ---------- dtype probe: flags[0]=floats-are-bf16, flags[1]=ints-are-int64 ----
__global__ __launch_bounds__(64)
void k_probe(const u16* __restrict__ xu, const int* __restrict__ ei,
             int* __restrict__ flags) {
    int lane = threadIdx.x;
    u16 h = xu[2 * lane];
    u32 E = (h >> 7) & 0xFF;
    int sane = (h == 0) || (E >= 90 && E <= 140);
    unsigned long long m = __ballot(sane);
    int cnt = __popcll(m);
    int z = (lane < 16) ? ei[2 * lane + 1] : 0;
    unsigned long long nz = __ballot(z != 0);
    if (lane == 0) {
        flags[0] = (cnt >= 48) ? 1 : 0;
        flags[1] = (nz == 0ull) ? 1 : 0;
    }
}

__device__ __forceinline__ int ld_row(const int* ei, int e, int is64) {
    return is64 ? ei[2 * (size_t)e] : ei[e];
}
__device__ __forceinline__ int ld_col(const int* ei, int e, int is64) {
    return is64 ? ei[2 * ((size_t)N_EDGES + e)] : ei[(size_t)N_EDGES + e];
}

// ---------- prep: Wt bf16 staging + fp32 conversion of MLP params ----------
__global__ __launch_bounds__(256)
void k_prep(const void* __restrict__ WM, const void* __restrict__ WA,
            const void* __restrict__ WS, const void* __restrict__ W1,
            const void* __restrict__ bM, const void* __restrict__ bA,
            const void* __restrict__ b1, const void* __restrict__ W2,
            const void* __restrict__ b2,
            u16* __restrict__ Wt, float* __restrict__ W1t,
            float* __restrict__ bMf, float* __restrict__ bAf,
            float* __restrict__ b1f, float* __restrict__ W2f,
            float* __restrict__ b2f, const int* __restrict__ flags) {
    const int isbf = flags[0];
    int t = blockIdx.x * 256 + threadIdx.x;
    if (t < F_CAT * K_PAD) {
        int n = t / K_PAD, k = t - n * K_PAD;
        u16 v = 0;
        if (k < F_IN) {
            const void* W = (n < 48) ? WM : (n < 96) ? WA : WS;
            int nn = (n < 48) ? n : (n < 96) ? n - 48 : n - 96;
            if (isbf) v = ((const u16*)W)[(size_t)k * 48 + nn];
            else      v = f2bf(((const float*)W)[(size_t)k * 48 + nn]);
        }
        Wt[(size_t)n * K_PAD + k] = v;
        return;
    }
    t -= F_CAT * K_PAD;
    if (t < F_CAT * F_MID) {       // W1t[j][k] = W1[k][j]
        int j = t / F_CAT, k = t - j * F_CAT;
        W1t[t] = ldf(W1, (size_t)k * F_MID + j, isbf);
        return;
    }
    t -= F_CAT * F_MID;
    if (t < 48)            { bMf[t] = ldf(bM, t, isbf); return; }
    t -= 48;
    if (t < 48)            { bAf[t] = ldf(bA, t, isbf); return; }
    t -= 48;
    if (t < 64)            { b1f[t] = ldf(b1, t, isbf); return; }
    t -= 64;
    if (t < 64)            { W2f[t] = ldf(W2, t, isbf); return; }
    t -= 64;
    if (t < 1)             { b2f[0] = ldf(b2, 0, isbf); return; }
}

__global__ __launch_bounds__(256)
void k_init(int* __restrict__ count) {
    int i = blockIdx.x * 256 + threadIdx.x;
    if (i < N_NODES) count[i] = 0;
}

__global__ __launch_bounds__(256)
void k_epass1(const int* __restrict__ ei, int* __restrict__ count,
              const int* __restrict__ flags) {
    const int is64 = flags[1];
    int e = blockIdx.x * 256 + threadIdx.x;
    if (e >= N_EDGES) return;
    atomicAdd(&count[ld_col(ei, e, is64)], 1);
}

__global__ __launch_bounds__(1024)
void k_scan(const int* __restrict__ count, int* __restrict__ rowptr,
            int* __restrict__ cursor) {
    __shared__ int part[1024];
    const int tid = threadIdx.x;
    const int CH = 52;                 // 1024*52 = 53248 >= 50000, CH%4==0
    int base = tid * CH;
    int s = 0;
#pragma unroll
    for (int i = 0; i < CH / 4; ++i) {
        int idx = base + 4 * i;
        if (idx < N_NODES) {           // N_NODES%4==0 -> full int4 in bounds
            int4 v = *(const int4*)(count + idx);
            s += v.x + v.y + v.z + v.w;
        }
    }
    part[tid] = s;
    __syncthreads();
    for (int off = 1; off < 1024; off <<= 1) {
        int v = (tid >= off) ? part[tid - off] : 0;
        __syncthreads();
        part[tid] += v;
        __syncthreads();
    }
    int run = part[tid] - s;           // exclusive prefix of this chunk
#pragma unroll
    for (int i = 0; i < CH / 4; ++i) {
        int idx = base + 4 * i;
        if (idx < N_NODES) {
            int4 v = *(const int4*)(count + idx);
            int4 rp;
            rp.x = run; run += v.x;
            rp.y = run; run += v.y;
            rp.z = run; run += v.z;
            rp.w = run; run += v.w;
            *(int4*)(rowptr + idx) = rp;
            *(int4*)(cursor + idx) = rp;
        }
    }
    if (tid == 1023) rowptr[N_NODES] = part[1023];
}

// place raw (src, w) into CSR slots; normalization happens in k_agg
__global__ __launch_bounds__(256)
void k_epass2(const int* __restrict__ ei, const void* __restrict__ ew,
              int* __restrict__ cursor, int* __restrict__ csr_src,
              float* __restrict__ csr_w, const int* __restrict__ flags) {
    const int isbf = flags[0], is64 = flags[1];
    int e = blockIdx.x * 256 + threadIdx.x;
    if (e >= N_EDGES) return;
    int r = ld_row(ei, e, is64);
    int c = ld_col(ei, e, is64);
    float w = ldf(ew, e, isbf);
    int p = atomicAdd(&cursor[c], 1);
    csr_src[p] = r;
    csr_w[p] = w;
}

// deg/dis from CSR segments, no atomics: one wave per node
__global__ __launch_bounds__(256)
void k_deg(const int* __restrict__ rowptr, const float* __restrict__ csr_w,
           float* __restrict__ dis) {
    const int lane = threadIdx.x & 63;
    const int node = blockIdx.x * 4 + (threadIdx.x >> 6);
    int start = rowptr[node], end = rowptr[node + 1];
    float s = 0.f;
    for (int i = start + lane; i < end; i += 64) s += csr_w[i];
#pragma unroll
    for (int off = 32; off > 0; off >>= 1) s += __shfl_down(s, off, 64);
    if (lane == 0) dis[node] = rsqrtf(1.0f + s);   // +1 = self-loop
}

// ---------- GEMM: H[50000 x 144] = x @ [WM|WA|WS] via bf16 MFMA ----------
// 2 M-tiles (32 rows) per wave for B-fragment reuse
__global__ __launch_bounds__(256)
void k_gemm(const void* __restrict__ x, const u16* __restrict__ Wt,
            float* __restrict__ hMA, float* __restrict__ xLin,
            const void* __restrict__ bS, const int* __restrict__ flags) {
    const int isbf = flags[0];
    const int lane = threadIdx.x & 63;
    const int wave = threadIdx.x >> 6;
    const int mrow = lane & 15;
    const int q    = lane >> 4;
    const int m_base = blockIdx.x * 128 + wave * 32;

    floatx4 acc[2][9];
#pragma unroll
    for (int tt = 0; tt < 2; ++tt)
#pragma unroll
        for (int t = 0; t < 9; ++t) {
            acc[tt][t][0]=0.f; acc[tt][t][1]=0.f; acc[tt][t][2]=0.f; acc[tt][t][3]=0.f;
        }

    for (int k0 = 0; k0 < K_PAD; k0 += 32) {
        int k = k0 + q * 8;
        short8 a[2];
#pragma unroll
        for (int tt = 0; tt < 2; ++tt) {
            int node = m_base + tt * 16 + mrow;
            short8 av = {0,0,0,0,0,0,0,0};
            if (node < N_NODES && k < F_IN) {
                if (isbf) {
                    av = *(const short8*)((const u16*)x + (size_t)node * F_IN + k);
                } else {
                    const float* xf = (const float*)x + (size_t)node * F_IN + k;
                    floatx4 v0 = *(const floatx4*)xf;
                    floatx4 v1 = *(const floatx4*)(xf + 4);
                    av[0]=(short)f2bf(v0[0]); av[1]=(short)f2bf(v0[1]);
                    av[2]=(short)f2bf(v0[2]); av[3]=(short)f2bf(v0[3]);
                    av[4]=(short)f2bf(v1[0]); av[5]=(short)f2bf(v1[1]);
                    av[6]=(short)f2bf(v1[2]); av[7]=(short)f2bf(v1[3]);
                }
            }
            a[tt] = av;
        }
#pragma unroll
        for (int t = 0; t < 9; ++t) {
            short8 b = *(const short8*)(Wt + (size_t)(t * 16 + mrow) * K_PAD + k);
            acc[0][t] = __builtin_amdgcn_mfma_f32_16x16x32_bf16(a[0], b, acc[0][t], 0, 0, 0);
            acc[1][t] = __builtin_amdgcn_mfma_f32_16x16x32_bf16(a[1], b, acc[1][t], 0, 0, 0);
        }
    }
#pragma unroll
    for (int tt = 0; tt < 2; ++tt)
#pragma unroll
    for (int t = 0; t < 9; ++t) {
        int n = t * 16 + mrow;                      // C/D col = lane&15
#pragma unroll
        for (int r = 0; r < 4; ++r) {
            int row = m_base + tt * 16 + q * 4 + r; // C/D row = (lane>>4)*4 + reg
            if (row < N_NODES) {
                float v = acc[tt][t][r];
                if (n < 96) hMA[(size_t)row * 96 + n] = v;
                else        xLin[(size_t)row * 48 + (n - 96)] =
                                fmaxf(v + ldf(bS, n - 96, isbf), 0.f);
            }
        }
    }
}

// ---------- fused aggregation + MLP: one wave per node, 5 edges in flight ----
__global__ __launch_bounds__(256)
void k_agg(const float* __restrict__ hMA, const float* __restrict__ xLin,
           const int* __restrict__ rowptr, const int* __restrict__ csr_src,
           const float* __restrict__ csr_w, const float* __restrict__ dis,
           const float* __restrict__ bMf, const float* __restrict__ bAf,
           const float* __restrict__ W1t, const float* __restrict__ b1f,
           const float* __restrict__ W2f, const float* __restrict__ b2f,
           void* __restrict__ out, const int* __restrict__ flags) {
    __shared__ __align__(16) float hsh[4][F_CAT];
    const int isbf = flags[0];
    const int lane = threadIdx.x & 63;
    const int wave = threadIdx.x >> 6;
    const int node = blockIdx.x * 4 + wave;   // grid = 12500*4 == 50000 exactly

    const int g = lane / 12;                  // edge group 0..5 (g==5: lanes 60-63 pad)
    const int s = lane - g * 12;              // feature slot 0..11 (8 floats each)
    const bool active = lane < 60;
    const bool isMax = s < 6;                 // slots 0..5: hM max, 6..11: hA sum

    const int start = rowptr[node];
    const int end   = rowptr[node + 1];
    const float dn  = dis[node];
    const float dn2 = dn * dn;                // self-loop norm

    // seed with self-loop contribution.
    // BUGFIX (round 3): max lanes may seed in every group (idempotent under
    // max), but SUM lanes must seed only in group 0 — otherwise the
    // self-loop is counted 5x after the cross-group combine.
    floatx4 a0, a1;
    {
        const float* nrow = hMA + (size_t)node * 96 + 8 * s;
        floatx4 v0 = *(const floatx4*)nrow;
        floatx4 v1 = *(const floatx4*)(nrow + 4);
        float seed = (isMax || g == 0) ? dn2 : 0.f;
        a0 = seed * v0; a1 = seed * v1;
    }

    for (int e0 = start; e0 < end; e0 += 5) {
        int e = e0 + g;
        bool valid = active && (e < end);
        int idx = (e < end) ? e : (end - 1);  // only used when end > start
        int r   = csr_src[idx];
        float w = csr_w[idx];
        float nm = w * dis[r] * dn;
        if (!valid) { r = node; nm = isMax ? dn2 : 0.f; }  // idempotent / zero pad
        const float* row = hMA + (size_t)r * 96 + 8 * s;
        floatx4 v0 = *(const floatx4*)row;
        floatx4 v1 = *(const floatx4*)(row + 4);
        floatx4 m0 = nm * v0, m1 = nm * v1;
        if (isMax) { a0 = max4(a0, m0); a1 = max4(a1, m1); }
        else       { a0 += m0;          a1 += m1; }
    }

    // combine the 5 groups into lanes 0..11
#pragma unroll
    for (int gg = 1; gg < 5; ++gg) {
        int src = lane + 12 * gg;
        floatx4 t0, t1;
#pragma unroll
        for (int j = 0; j < 4; ++j) {
            t0[j] = __shfl(a0[j], src, 64);
            t1[j] = __shfl(a1[j], src, 64);
        }
        if (lane < 12) {
            if (isMax) { a0 = max4(a0, t0); a1 = max4(a1, t1); }
            else       { a0 += t0;          a1 += t1; }
        }
    }

    if (lane < 12) {
        const float* bp = isMax ? (bMf + 8 * lane) : (bAf + 8 * lane - 48);
        floatx4 r0, r1;
#pragma unroll
        for (int j = 0; j < 4; ++j) {
            r0[j] = fmaxf(a0[j] + bp[j],     0.f);
            r1[j] = fmaxf(a1[j] + bp[4 + j], 0.f);
        }
        *(floatx4*)(&hsh[wave][8 * lane])     = r0;
        *(floatx4*)(&hsh[wave][8 * lane + 4]) = r1;
    } else if (lane < 18) {
        const float* xr = xLin + (size_t)node * 48 + 8 * (lane - 12);
        *(floatx4*)(&hsh[wave][96 + 8 * (lane - 12)])     = *(const floatx4*)xr;
        *(floatx4*)(&hsh[wave][96 + 8 * (lane - 12) + 4]) = *(const floatx4*)(xr + 4);
    }
    __syncthreads();

    // MLP: lane j computes mid[j]; W1t[j][k] fp32, float4 loads
    float mid = b1f[lane];
    const float* wrow = W1t + (size_t)lane * F_CAT;
    for (int k = 0; k < F_CAT; k += 4) {
        floatx4 h  = *(const floatx4*)(&hsh[wave][k]);
        floatx4 ww = *(const floatx4*)(wrow + k);
        mid = fmaf(h[0], ww[0], mid);
        mid = fmaf(h[1], ww[1], mid);
        mid = fmaf(h[2], ww[2], mid);
        mid = fmaf(h[3], ww[3], mid);
    }
    mid = fmaxf(mid, 0.f);
    float c2 = mid * W2f[lane];
#pragma unroll
    for (int off = 32; off > 0; off >>= 1) c2 += __shfl_down(c2, off, 64);
    if (lane == 0) {
        float res = c2 + b2f[0];
        if (isbf) ((u16*)out)[node] = f2bf(res);
        else      ((float*)out)[node] = res;
    }
}

extern "C" void kernel_launch(void* const* d_in, const int* in_sizes, int n_in,
                              void* d_out, int out_size, void* d_ws, size_t ws_size,
                              hipStream_t stream) {
    const void* x  = d_in[0];
    const int*  ei = (const int*)d_in[1];
    const void* ew = d_in[2];
    const void* WM = d_in[3];
    const void* bM = d_in[4];
    const void* WA = d_in[5];
    const void* bA = d_in[6];
    const void* WS = d_in[7];
    const void* bS = d_in[8];
    const void* W1 = d_in[9];
    const void* b1 = d_in[10];
    const void* W2 = d_in[11];
    const void* b2 = d_in[12];

    char* p = (char*)d_ws;
    auto alloc = [&](size_t bytes) -> char* {
        char* r = p; p += (bytes + 255) & ~(size_t)255; return r;
    };
    int*   flags   = (int*)  alloc(16);
    float* dis     = (float*)alloc((size_t)N_NODES * 4);
    int*   count   = (int*)  alloc((size_t)N_NODES * 4);
    int*   rowptr  = (int*)  alloc((size_t)(N_NODES + 1) * 4);
    int*   cursor  = (int*)  alloc((size_t)N_NODES * 4);
    int*   csr_src = (int*)  alloc((size_t)N_EDGES * 4);
    float* csr_w   = (float*)alloc((size_t)N_EDGES * 4);
    float* hMA     = (float*)alloc((size_t)N_NODES * 96 * 4);
    float* xLin    = (float*)alloc((size_t)N_NODES * 48 * 4);
    u16*   Wt      = (u16*)  alloc((size_t)F_CAT * K_PAD * 2);
    float* W1t     = (float*)alloc((size_t)F_CAT * F_MID * 4);
    float* bMf     = (float*)alloc(48 * 4);
    float* bAf     = (float*)alloc(48 * 4);
    float* b1f     = (float*)alloc(64 * 4);
    float* W2f     = (float*)alloc(64 * 4);
    float* b2f     = (float*)alloc(4);

    k_probe <<<1, 64, 0, stream>>>((const u16*)x, ei, flags);
    k_prep  <<<(F_CAT * K_PAD + F_CAT * F_MID + 225 + 255) / 256, 256, 0, stream>>>(
                 WM, WA, WS, W1, bM, bA, b1, W2, b2,
                 Wt, W1t, bMf, bAf, b1f, W2f, b2f, flags);
    k_init  <<<(N_NODES + 255) / 256, 256, 0, stream>>>(count);
    k_epass1<<<(N_EDGES + 255) / 256, 256, 0, stream>>>(ei, count, flags);
    k_scan  <<<1, 1024, 0, stream>>>(count, rowptr, cursor);
    k_epass2<<<(N_EDGES + 255) / 256, 256, 0, stream>>>(ei, ew, cursor, csr_src, csr_w, flags);
    k_deg   <<<(N_NODES + 3) / 4, 256, 0, stream>>>(rowptr, csr_w, dis);
    k_gemm  <<<(N_NODES + 127) / 128, 256, 0, stream>>>(x, Wt, hMA, xLin, bS, flags);
    k_agg   <<<N_NODES / 4, 256, 0, stream>>>(hMA, xLin, rowptr, csr_src, csr_w, dis,
                                              bMf, bAf, W1t, b1f, W2f, b2f, d_out, flags);
    (void)in_sizes; (void)n_in; (void)out_size; (void)ws_size;
}

// Round 5
// 449.023 us; speedup vs baseline: 1.6546x; 1.2316x over previous
//
#include <hip/hip_runtime.h>
#include <stdint.h>

#define N_NODES 50000
#define N_EDGES 1600000
#define F_IN    264
#define F_HID   48
#define F_CAT   144
#define F_MID   64
#define K_PAD   288   // 264 padded up to multiple of 32

typedef unsigned short u16;
typedef unsigned int   u32;

using short8  = __attribute__((ext_vector_type(8))) short;
using floatx4 = __attribute__((ext_vector_type(4))) float;

__device__ __forceinline__ float bf2f(u16 u) {
    return __uint_as_float(((u32)u) << 16);
}
__device__ __forceinline__ u16 f2bf(float f) {
    u32 u = __float_as_uint(f);
    u32 r = (u + 0x7fffu + ((u >> 16) & 1u)) >> 16;   // round-nearest-even
    return (u16)r;
}
// dtype-agnostic scalar float load: isbf ? bf16[i] : f32[i]
__device__ __forceinline__ float ldf(const void* p, size_t i, int isbf) {
    return isbf ? bf2f(((const u16*)p)[i]) : ((const float*)p)[i];
}
__device__ __forceinline__ floatx4 max4(floatx4 a, floatx4 b) {
    floatx4 r;
    r[0] = fmaxf(a[0], b[0]); r[1] = fmaxf(a[1], b[1]);
    r[2] = fmaxf(a[2], b[2]); r[3] = fmaxf(a[3], b[3]);
    return r;
}

// ---------- dtype probe: flags[0]=floats-are-bf16, flags[1]=ints-are-int64 ----
__global__ __launch_bounds__(64)
void k_probe(const u16* __restrict__ xu, const int* __restrict__ ei,
             int* __restrict__ flags) {
    int lane = threadIdx.x;
    u16 h = xu[2 * lane];
    u32 E = (h >> 7) & 0xFF;
    int sane = (h == 0) || (E >= 90 && E <= 140);
    unsigned long long m = __ballot(sane);
    int cnt = __popcll(m);
    int z = (lane < 16) ? ei[2 * lane + 1] : 0;
    unsigned long long nz = __ballot(z != 0);
    if (lane == 0) {
        flags[0] = (cnt >= 48) ? 1 : 0;
        flags[1] = (nz == 0ull) ? 1 : 0;
    }
}

__device__ __forceinline__ int ld_row(const int* ei, int e, int is64) {
    return is64 ? ei[2 * (size_t)e] : ei[e];
}
__device__ __forceinline__ int ld_col(const int* ei, int e, int is64) {
    return is64 ? ei[2 * ((size_t)N_EDGES + e)] : ei[(size_t)N_EDGES + e];
}

// ---------- prep: Wt bf16 staging + fp32 conversion of MLP params ----------
__global__ __launch_bounds__(256)
void k_prep(const void* __restrict__ WM, const void* __restrict__ WA,
            const void* __restrict__ WS, const void* __restrict__ W1,
            const void* __restrict__ bM, const void* __restrict__ bA,
            const void* __restrict__ b1, const void* __restrict__ W2,
            const void* __restrict__ b2,
            u16* __restrict__ Wt, float* __restrict__ W1t,
            float* __restrict__ bMf, float* __restrict__ bAf,
            float* __restrict__ b1f, float* __restrict__ W2f,
            float* __restrict__ b2f, const int* __restrict__ flags) {
    const int isbf = flags[0];
    int t = blockIdx.x * 256 + threadIdx.x;
    if (t < F_CAT * K_PAD) {
        int n = t / K_PAD, k = t - n * K_PAD;
        u16 v = 0;
        if (k < F_IN) {
            const void* W = (n < 48) ? WM : (n < 96) ? WA : WS;
            int nn = (n < 48) ? n : (n < 96) ? n - 48 : n - 96;
            if (isbf) v = ((const u16*)W)[(size_t)k * 48 + nn];
            else      v = f2bf(((const float*)W)[(size_t)k * 48 + nn]);
        }
        Wt[(size_t)n * K_PAD + k] = v;
        return;
    }
    t -= F_CAT * K_PAD;
    if (t < F_CAT * F_MID) {       // W1t[j][k] = W1[k][j]
        int j = t / F_CAT, k = t - j * F_CAT;
        W1t[t] = ldf(W1, (size_t)k * F_MID + j, isbf);
        return;
    }
    t -= F_CAT * F_MID;
    if (t < 48)            { bMf[t] = ldf(bM, t, isbf); return; }
    t -= 48;
    if (t < 48)            { bAf[t] = ldf(bA, t, isbf); return; }
    t -= 48;
    if (t < 64)            { b1f[t] = ldf(b1, t, isbf); return; }
    t -= 64;
    if (t < 64)            { W2f[t] = ldf(W2, t, isbf); return; }
    t -= 64;
    if (t < 1)             { b2f[0] = ldf(b2, 0, isbf); return; }
}

__global__ __launch_bounds__(256)
void k_init(int* __restrict__ count) {
    int i = blockIdx.x * 256 + threadIdx.x;
    if (i < N_NODES) count[i] = 0;
}

// pass 1: per-edge within-column rank + column counts (the ONLY atomic pass)
__global__ __launch_bounds__(256)
void k_epass1(const int* __restrict__ ei, int* __restrict__ count,
              int* __restrict__ rank, const int* __restrict__ flags) {
    const int is64 = flags[1];
    int e = blockIdx.x * 256 + threadIdx.x;
    if (e >= N_EDGES) return;
    int c = ld_col(ei, e, is64);
    rank[e] = atomicAdd(&count[c], 1);
}

__global__ __launch_bounds__(1024)
void k_scan(const int* __restrict__ count, int* __restrict__ rowptr) {
    __shared__ int part[1024];
    const int tid = threadIdx.x;
    const int CH = 52;                 // 1024*52 = 53248 >= 50000, CH%4==0
    int base = tid * CH;
    int s = 0;
#pragma unroll
    for (int i = 0; i < CH / 4; ++i) {
        int idx = base + 4 * i;
        if (idx < N_NODES) {           // N_NODES%4==0 -> full int4 in bounds
            int4 v = *(const int4*)(count + idx);
            s += v.x + v.y + v.z + v.w;
        }
    }
    part[tid] = s;
    __syncthreads();
    for (int off = 1; off < 1024; off <<= 1) {
        int v = (tid >= off) ? part[tid - off] : 0;
        __syncthreads();
        part[tid] += v;
        __syncthreads();
    }
    int run = part[tid] - s;           // exclusive prefix of this chunk
#pragma unroll
    for (int i = 0; i < CH / 4; ++i) {
        int idx = base + 4 * i;
        if (idx < N_NODES) {
            int4 v = *(const int4*)(count + idx);
            int4 rp;
            rp.x = run; run += v.x;
            rp.y = run; run += v.y;
            rp.z = run; run += v.z;
            rp.w = run; run += v.w;
            *(int4*)(rowptr + idx) = rp;
        }
    }
    if (tid == 1023) rowptr[N_NODES] = part[1023];
}

// pass 2: atomic-free placement — one scattered 8B store per edge
__global__ __launch_bounds__(256)
void k_epass2(const int* __restrict__ ei, const void* __restrict__ ew,
              const int* __restrict__ rowptr, const int* __restrict__ rank,
              int2* __restrict__ csr_pair, const int* __restrict__ flags) {
    const int isbf = flags[0], is64 = flags[1];
    int e = blockIdx.x * 256 + threadIdx.x;
    if (e >= N_EDGES) return;
    int r = ld_row(ei, e, is64);
    int c = ld_col(ei, e, is64);
    float w = ldf(ew, e, isbf);
    int p = rowptr[c] + rank[e];
    csr_pair[p] = make_int2(r, __float_as_int(w));
}

// deg/dis from CSR segments, no atomics: one wave per node
__global__ __launch_bounds__(256)
void k_deg(const int* __restrict__ rowptr, const int2* __restrict__ csr_pair,
           float* __restrict__ dis) {
    const int lane = threadIdx.x & 63;
    const int node = blockIdx.x * 4 + (threadIdx.x >> 6);
    int start = rowptr[node], end = rowptr[node + 1];
    float s = 0.f;
    for (int i = start + lane; i < end; i += 64)
        s += __int_as_float(csr_pair[i].y);
#pragma unroll
    for (int off = 32; off > 0; off >>= 1) s += __shfl_down(s, off, 64);
    if (lane == 0) dis[node] = rsqrtf(1.0f + s);   // +1 = self-loop
}

// fold dis[src] into the stored weight: pair.y <- w * dis[src]
__global__ __launch_bounds__(256)
void k_norm(int2* __restrict__ csr_pair, const float* __restrict__ dis) {
    int e = blockIdx.x * 256 + threadIdx.x;
    if (e >= N_EDGES) return;
    int2 pr = csr_pair[e];
    float w = __int_as_float(pr.y) * dis[pr.x];
    csr_pair[e].y = __float_as_int(w);
}

// ---------- GEMM: H[50000 x 144] = x @ [WM|WA|WS] via bf16 MFMA ----------
// hMB[node][96] stored bf16 (halves k_agg gather traffic); xLin fp32+bias+relu
__global__ __launch_bounds__(256)
void k_gemm(const void* __restrict__ x, const u16* __restrict__ Wt,
            u16* __restrict__ hMB, float* __restrict__ xLin,
            const void* __restrict__ bS, const int* __restrict__ flags) {
    const int isbf = flags[0];
    const int lane = threadIdx.x & 63;
    const int wave = threadIdx.x >> 6;
    const int mrow = lane & 15;
    const int q    = lane >> 4;
    const int m_base = blockIdx.x * 128 + wave * 32;

    floatx4 acc[2][9];
#pragma unroll
    for (int tt = 0; tt < 2; ++tt)
#pragma unroll
        for (int t = 0; t < 9; ++t) {
            acc[tt][t][0]=0.f; acc[tt][t][1]=0.f; acc[tt][t][2]=0.f; acc[tt][t][3]=0.f;
        }

    for (int k0 = 0; k0 < K_PAD; k0 += 32) {
        int k = k0 + q * 8;
        short8 a[2];
#pragma unroll
        for (int tt = 0; tt < 2; ++tt) {
            int node = m_base + tt * 16 + mrow;
            short8 av = {0,0,0,0,0,0,0,0};
            if (node < N_NODES && k < F_IN) {
                if (isbf) {
                    av = *(const short8*)((const u16*)x + (size_t)node * F_IN + k);
                } else {
                    const float* xf = (const float*)x + (size_t)node * F_IN + k;
                    floatx4 v0 = *(const floatx4*)xf;
                    floatx4 v1 = *(const floatx4*)(xf + 4);
                    av[0]=(short)f2bf(v0[0]); av[1]=(short)f2bf(v0[1]);
                    av[2]=(short)f2bf(v0[2]); av[3]=(short)f2bf(v0[3]);
                    av[4]=(short)f2bf(v1[0]); av[5]=(short)f2bf(v1[1]);
                    av[6]=(short)f2bf(v1[2]); av[7]=(short)f2bf(v1[3]);
                }
            }
            a[tt] = av;
        }
#pragma unroll
        for (int t = 0; t < 9; ++t) {
            short8 b = *(const short8*)(Wt + (size_t)(t * 16 + mrow) * K_PAD + k);
            acc[0][t] = __builtin_amdgcn_mfma_f32_16x16x32_bf16(a[0], b, acc[0][t], 0, 0, 0);
            acc[1][t] = __builtin_amdgcn_mfma_f32_16x16x32_bf16(a[1], b, acc[1][t], 0, 0, 0);
        }
    }
#pragma unroll
    for (int tt = 0; tt < 2; ++tt)
#pragma unroll
    for (int t = 0; t < 9; ++t) {
        int n = t * 16 + mrow;                      // C/D col = lane&15
#pragma unroll
        for (int r = 0; r < 4; ++r) {
            int row = m_base + tt * 16 + q * 4 + r; // C/D row = (lane>>4)*4 + reg
            if (row < N_NODES) {
                float v = acc[tt][t][r];
                if (n < 96) hMB[(size_t)row * 96 + n] = f2bf(v);
                else        xLin[(size_t)row * 48 + (n - 96)] =
                                fmaxf(v + ldf(bS, n - 96, isbf), 0.f);
            }
        }
    }
}

// ---------- fused aggregation + MLP: one wave per node, 10 edges in flight ---
__global__ __launch_bounds__(256)
void k_agg(const u16* __restrict__ hMB, const float* __restrict__ xLin,
           const int* __restrict__ rowptr, const int2* __restrict__ csr_pair,
           const float* __restrict__ dis,
           const float* __restrict__ bMf, const float* __restrict__ bAf,
           const float* __restrict__ W1t, const float* __restrict__ b1f,
           const float* __restrict__ W2f, const float* __restrict__ b2f,
           void* __restrict__ out, const int* __restrict__ flags) {
    __shared__ __align__(16) float hsh[4][F_CAT];
    const int isbf = flags[0];
    const int lane = threadIdx.x & 63;
    const int wave = threadIdx.x >> 6;
    const int node = blockIdx.x * 4 + wave;   // grid = 12500*4 == 50000 exactly

    const int g = lane / 12;                  // edge group 0..5 (g==5: lanes 60-63 pad)
    const int s = lane - g * 12;              // feature slot 0..11 (8 bf16 each)
    const bool active = lane < 60;
    const bool isMax = s < 6;                 // slots 0..5: hM max, 6..11: hA sum

    const int start = rowptr[node];
    const int end   = rowptr[node + 1];
    const float dn  = dis[node];
    const float dn2 = dn * dn;                // self-loop norm

    // self row (bf16), also reused as the pad row
    const u16* nrow = hMB + (size_t)node * 96 + 8 * s;

    // seed with self-loop contribution.
    // max lanes may seed in every group (idempotent under max); SUM lanes
    // seed only in group 0 (else self-loop counted 5x after combine).
    floatx4 a0, a1;
    {
        short8 rv = *(const short8*)nrow;
        float seed = (isMax || g == 0) ? dn2 : 0.f;
#pragma unroll
        for (int j = 0; j < 4; ++j) {
            a0[j] = seed * bf2f((u16)rv[j]);
            a1[j] = seed * bf2f((u16)rv[4 + j]);
        }
    }

    for (int e0 = start; e0 < end; e0 += 10) {
#pragma unroll
        for (int b = 0; b < 2; ++b) {
            int e = e0 + 5 * b + g;
            bool valid = active && (e < end);
            int idx = (e < end) ? e : (end - 1);     // only used when end > start
            int2 pr = csr_pair[idx];                  // {src, w*dis[src]}
            int r = pr.x;
            float nm = __int_as_float(pr.y) * dn;
            const u16* rowp;
            if (!valid) { rowp = nrow; nm = isMax ? dn2 : 0.f; }  // idempotent / zero
            else        { rowp = hMB + (size_t)r * 96 + 8 * s; }
            short8 rv = *(const short8*)rowp;
            floatx4 m0, m1;
#pragma unroll
            for (int j = 0; j < 4; ++j) {
                m0[j] = nm * bf2f((u16)rv[j]);
                m1[j] = nm * bf2f((u16)rv[4 + j]);
            }
            if (isMax) { a0 = max4(a0, m0); a1 = max4(a1, m1); }
            else       { a0 += m0;          a1 += m1; }
        }
    }

    // combine the 5 groups into lanes 0..11
#pragma unroll
    for (int gg = 1; gg < 5; ++gg) {
        int src = lane + 12 * gg;
        floatx4 t0, t1;
#pragma unroll
        for (int j = 0; j < 4; ++j) {
            t0[j] = __shfl(a0[j], src, 64);
            t1[j] = __shfl(a1[j], src, 64);
        }
        if (lane < 12) {
            if (isMax) { a0 = max4(a0, t0); a1 = max4(a1, t1); }
            else       { a0 += t0;          a1 += t1; }
        }
    }

    if (lane < 12) {
        const float* bp = isMax ? (bMf + 8 * lane) : (bAf + 8 * lane - 48);
        floatx4 r0, r1;
#pragma unroll
        for (int j = 0; j < 4; ++j) {
            r0[j] = fmaxf(a0[j] + bp[j],     0.f);
            r1[j] = fmaxf(a1[j] + bp[4 + j], 0.f);
        }
        *(floatx4*)(&hsh[wave][8 * lane])     = r0;
        *(floatx4*)(&hsh[wave][8 * lane + 4]) = r1;
    } else if (lane < 18) {
        const float* xr = xLin + (size_t)node * 48 + 8 * (lane - 12);
        *(floatx4*)(&hsh[wave][96 + 8 * (lane - 12)])     = *(const floatx4*)xr;
        *(floatx4*)(&hsh[wave][96 + 8 * (lane - 12) + 4]) = *(const floatx4*)(xr + 4);
    }
    __syncthreads();

    // MLP: lane j computes mid[j]; W1t[j][k] fp32, float4 loads
    float mid = b1f[lane];
    const float* wrow = W1t + (size_t)lane * F_CAT;
    for (int k = 0; k < F_CAT; k += 4) {
        floatx4 h  = *(const floatx4*)(&hsh[wave][k]);
        floatx4 ww = *(const floatx4*)(wrow + k);
        mid = fmaf(h[0], ww[0], mid);
        mid = fmaf(h[1], ww[1], mid);
        mid = fmaf(h[2], ww[2], mid);
        mid = fmaf(h[3], ww[3], mid);
    }
    mid = fmaxf(mid, 0.f);
    float c2 = mid * W2f[lane];
#pragma unroll
    for (int off = 32; off > 0; off >>= 1) c2 += __shfl_down(c2, off, 64);
    if (lane == 0) {
        float res = c2 + b2f[0];
        if (isbf) ((u16*)out)[node] = f2bf(res);
        else      ((float*)out)[node] = res;
    }
}

extern "C" void kernel_launch(void* const* d_in, const int* in_sizes, int n_in,
                              void* d_out, int out_size, void* d_ws, size_t ws_size,
                              hipStream_t stream) {
    const void* x  = d_in[0];
    const int*  ei = (const int*)d_in[1];
    const void* ew = d_in[2];
    const void* WM = d_in[3];
    const void* bM = d_in[4];
    const void* WA = d_in[5];
    const void* bA = d_in[6];
    const void* WS = d_in[7];
    const void* bS = d_in[8];
    const void* W1 = d_in[9];
    const void* b1 = d_in[10];
    const void* W2 = d_in[11];
    const void* b2 = d_in[12];

    char* p = (char*)d_ws;
    auto alloc = [&](size_t bytes) -> char* {
        char* r = p; p += (bytes + 255) & ~(size_t)255; return r;
    };
    int*   flags    = (int*)  alloc(16);
    float* dis      = (float*)alloc((size_t)N_NODES * 4);
    int*   count    = (int*)  alloc((size_t)N_NODES * 4);
    int*   rowptr   = (int*)  alloc((size_t)(N_NODES + 1) * 4);
    int*   rank     = (int*)  alloc((size_t)N_EDGES * 4);
    int2*  csr_pair = (int2*) alloc((size_t)N_EDGES * 8);
    u16*   hMB      = (u16*)  alloc((size_t)N_NODES * 96 * 2);
    float* xLin     = (float*)alloc((size_t)N_NODES * 48 * 4);
    u16*   Wt       = (u16*)  alloc((size_t)F_CAT * K_PAD * 2);
    float* W1t      = (float*)alloc((size_t)F_CAT * F_MID * 4);
    float* bMf      = (float*)alloc(48 * 4);
    float* bAf      = (float*)alloc(48 * 4);
    float* b1f      = (float*)alloc(64 * 4);
    float* W2f      = (float*)alloc(64 * 4);
    float* b2f      = (float*)alloc(4);

    k_probe <<<1, 64, 0, stream>>>((const u16*)x, ei, flags);
    k_prep  <<<(F_CAT * K_PAD + F_CAT * F_MID + 225 + 255) / 256, 256, 0, stream>>>(
                 WM, WA, WS, W1, bM, bA, b1, W2, b2,
                 Wt, W1t, bMf, bAf, b1f, W2f, b2f, flags);
    k_init  <<<(N_NODES + 255) / 256, 256, 0, stream>>>(count);
    k_epass1<<<(N_EDGES + 255) / 256, 256, 0, stream>>>(ei, count, rank, flags);
    k_scan  <<<1, 1024, 0, stream>>>(count, rowptr);
    k_epass2<<<(N_EDGES + 255) / 256, 256, 0, stream>>>(ei, ew, rowptr, rank, csr_pair, flags);
    k_deg   <<<(N_NODES + 3) / 4, 256, 0, stream>>>(rowptr, csr_pair, dis);
    k_norm  <<<(N_EDGES + 255) / 256, 256, 0, stream>>>(csr_pair, dis);
    k_gemm  <<<(N_NODES + 127) / 128, 256, 0, stream>>>(x, Wt, hMB, xLin, bS, flags);
    k_agg   <<<N_NODES / 4, 256, 0, stream>>>(hMB, xLin, rowptr, csr_pair, dis,
                                              bMf, bAf, W1t, b1f, W2f, b2f, d_out, flags);
    (void)in_sizes; (void)n_in; (void)out_size; (void)ws_size;
}

// Round 6
// 434.610 us; speedup vs baseline: 1.7095x; 1.0332x over previous
//
#include <hip/hip_runtime.h>
#include <stdint.h>

#define N_NODES 50000
#define N_EDGES 1600000
#define F_IN    264
#define F_HID   48
#define F_CAT   144
#define F_MID   64
#define K_PAD   288   // 264 padded up to multiple of 32

typedef unsigned short u16;
typedef unsigned int   u32;

using short8  = __attribute__((ext_vector_type(8))) short;
using floatx4 = __attribute__((ext_vector_type(4))) float;

__device__ __forceinline__ float bf2f(u16 u) {
    return __uint_as_float(((u32)u) << 16);
}
__device__ __forceinline__ u16 f2bf(float f) {
    u32 u = __float_as_uint(f);
    u32 r = (u + 0x7fffu + ((u >> 16) & 1u)) >> 16;   // round-nearest-even
    return (u16)r;
}
// dtype-agnostic scalar float load: isbf ? bf16[i] : f32[i]
__device__ __forceinline__ float ldf(const void* p, size_t i, int isbf) {
    return isbf ? bf2f(((const u16*)p)[i]) : ((const float*)p)[i];
}
__device__ __forceinline__ floatx4 max4(floatx4 a, floatx4 b) {
    floatx4 r;
    r[0] = fmaxf(a[0], b[0]); r[1] = fmaxf(a[1], b[1]);
    r[2] = fmaxf(a[2], b[2]); r[3] = fmaxf(a[3], b[3]);
    return r;
}

// ---------- dtype probe: flags[0]=floats-are-bf16, flags[1]=ints-are-int64 ----
__global__ __launch_bounds__(64)
void k_probe(const u16* __restrict__ xu, const int* __restrict__ ei,
             int* __restrict__ flags) {
    int lane = threadIdx.x;
    u16 h = xu[2 * lane];
    u32 E = (h >> 7) & 0xFF;
    int sane = (h == 0) || (E >= 90 && E <= 140);
    unsigned long long m = __ballot(sane);
    int cnt = __popcll(m);
    int z = (lane < 16) ? ei[2 * lane + 1] : 0;
    unsigned long long nz = __ballot(z != 0);
    if (lane == 0) {
        flags[0] = (cnt >= 48) ? 1 : 0;
        flags[1] = (nz == 0ull) ? 1 : 0;
    }
}

__device__ __forceinline__ int ld_row(const int* ei, int e, int is64) {
    return is64 ? ei[2 * (size_t)e] : ei[e];
}
__device__ __forceinline__ int ld_col(const int* ei, int e, int is64) {
    return is64 ? ei[2 * ((size_t)N_EDGES + e)] : ei[(size_t)N_EDGES + e];
}

// ---------- prep: Wt bf16 staging + fp32 conversion of MLP params ----------
__global__ __launch_bounds__(256)
void k_prep(const void* __restrict__ WM, const void* __restrict__ WA,
            const void* __restrict__ WS, const void* __restrict__ W1,
            const void* __restrict__ bM, const void* __restrict__ bA,
            const void* __restrict__ b1, const void* __restrict__ W2,
            const void* __restrict__ b2,
            u16* __restrict__ Wt, float* __restrict__ W1t,
            float* __restrict__ bMf, float* __restrict__ bAf,
            float* __restrict__ b1f, float* __restrict__ W2f,
            float* __restrict__ b2f, const int* __restrict__ flags) {
    const int isbf = flags[0];
    int t = blockIdx.x * 256 + threadIdx.x;
    if (t < F_CAT * K_PAD) {
        int n = t / K_PAD, k = t - n * K_PAD;
        u16 v = 0;
        if (k < F_IN) {
            const void* W = (n < 48) ? WM : (n < 96) ? WA : WS;
            int nn = (n < 48) ? n : (n < 96) ? n - 48 : n - 96;
            if (isbf) v = ((const u16*)W)[(size_t)k * 48 + nn];
            else      v = f2bf(((const float*)W)[(size_t)k * 48 + nn]);
        }
        Wt[(size_t)n * K_PAD + k] = v;
        return;
    }
    t -= F_CAT * K_PAD;
    if (t < F_CAT * F_MID) {       // W1t[j][k] = W1[k][j]
        int j = t / F_CAT, k = t - j * F_CAT;
        W1t[t] = ldf(W1, (size_t)k * F_MID + j, isbf);
        return;
    }
    t -= F_CAT * F_MID;
    if (t < 48)            { bMf[t] = ldf(bM, t, isbf); return; }
    t -= 48;
    if (t < 48)            { bAf[t] = ldf(bA, t, isbf); return; }
    t -= 48;
    if (t < 64)            { b1f[t] = ldf(b1, t, isbf); return; }
    t -= 64;
    if (t < 64)            { W2f[t] = ldf(W2, t, isbf); return; }
    t -= 64;
    if (t < 1)             { b2f[0] = ldf(b2, 0, isbf); return; }
}

// pass 1: per-edge within-column rank + column counts (the ONLY atomic pass)
__global__ __launch_bounds__(256)
void k_epass1(const int* __restrict__ ei, int* __restrict__ count,
              int* __restrict__ rank, const int* __restrict__ flags) {
    const int is64 = flags[1];
    int e = blockIdx.x * 256 + threadIdx.x;
    if (e >= N_EDGES) return;
    int c = ld_col(ei, e, is64);
    rank[e] = atomicAdd(&count[c], 1);
}

__global__ __launch_bounds__(1024)
void k_scan(const int* __restrict__ count, int* __restrict__ rowptr) {
    __shared__ int part[1024];
    const int tid = threadIdx.x;
    const int CH = 52;                 // 1024*52 = 53248 >= 50000, CH%4==0
    int base = tid * CH;
    int s = 0;
#pragma unroll
    for (int i = 0; i < CH / 4; ++i) {
        int idx = base + 4 * i;
        if (idx < N_NODES) {           // N_NODES%4==0 -> full int4 in bounds
            int4 v = *(const int4*)(count + idx);
            s += v.x + v.y + v.z + v.w;
        }
    }
    part[tid] = s;
    __syncthreads();
    for (int off = 1; off < 1024; off <<= 1) {
        int v = (tid >= off) ? part[tid - off] : 0;
        __syncthreads();
        part[tid] += v;
        __syncthreads();
    }
    int run = part[tid] - s;           // exclusive prefix of this chunk
#pragma unroll
    for (int i = 0; i < CH / 4; ++i) {
        int idx = base + 4 * i;
        if (idx < N_NODES) {
            int4 v = *(const int4*)(count + idx);
            int4 rp;
            rp.x = run; run += v.x;
            rp.y = run; run += v.y;
            rp.z = run; run += v.z;
            rp.w = run; run += v.w;
            *(int4*)(rowptr + idx) = rp;
        }
    }
    if (tid == 1023) rowptr[N_NODES] = part[1023];
}

// pass 2: atomic-free placement — one scattered 8B store per edge (raw w)
__global__ __launch_bounds__(256)
void k_epass2(const int* __restrict__ ei, const void* __restrict__ ew,
              const int* __restrict__ rowptr, const int* __restrict__ rank,
              int2* __restrict__ csr_pair, const int* __restrict__ flags) {
    const int isbf = flags[0], is64 = flags[1];
    int e = blockIdx.x * 256 + threadIdx.x;
    if (e >= N_EDGES) return;
    int r = ld_row(ei, e, is64);
    int c = ld_col(ei, e, is64);
    float w = ldf(ew, e, isbf);
    int p = rowptr[c] + rank[e];
    csr_pair[p] = make_int2(r, __float_as_int(w));
}

// deg/dis from CSR segments, no atomics: one wave per node
__global__ __launch_bounds__(256)
void k_deg(const int* __restrict__ rowptr, const int2* __restrict__ csr_pair,
           float* __restrict__ dis) {
    const int lane = threadIdx.x & 63;
    const int node = blockIdx.x * 4 + (threadIdx.x >> 6);
    int start = rowptr[node], end = rowptr[node + 1];
    float s = 0.f;
    for (int i = start + lane; i < end; i += 64)
        s += __int_as_float(csr_pair[i].y);
#pragma unroll
    for (int off = 32; off > 0; off >>= 1) s += __shfl_down(s, off, 64);
    if (lane == 0) dis[node] = rsqrtf(1.0f + s);   // +1 = self-loop
}

// ---------- GEMM: H[50000 x 144] = x @ [WM|WA|WS] via bf16 MFMA ----------
// hMB[node][96] stored bf16 (halves k_agg gather traffic); xLin fp32+bias+relu
__global__ __launch_bounds__(256)
void k_gemm(const void* __restrict__ x, const u16* __restrict__ Wt,
            u16* __restrict__ hMB, float* __restrict__ xLin,
            const void* __restrict__ bS, const int* __restrict__ flags) {
    const int isbf = flags[0];
    const int lane = threadIdx.x & 63;
    const int wave = threadIdx.x >> 6;
    const int mrow = lane & 15;
    const int q    = lane >> 4;
    const int m_base = blockIdx.x * 128 + wave * 32;

    floatx4 acc[2][9];
#pragma unroll
    for (int tt = 0; tt < 2; ++tt)
#pragma unroll
        for (int t = 0; t < 9; ++t) {
            acc[tt][t][0]=0.f; acc[tt][t][1]=0.f; acc[tt][t][2]=0.f; acc[tt][t][3]=0.f;
        }

    for (int k0 = 0; k0 < K_PAD; k0 += 32) {
        int k = k0 + q * 8;
        short8 a[2];
#pragma unroll
        for (int tt = 0; tt < 2; ++tt) {
            int node = m_base + tt * 16 + mrow;
            short8 av = {0,0,0,0,0,0,0,0};
            if (node < N_NODES && k < F_IN) {
                if (isbf) {
                    av = *(const short8*)((const u16*)x + (size_t)node * F_IN + k);
                } else {
                    const float* xf = (const float*)x + (size_t)node * F_IN + k;
                    floatx4 v0 = *(const floatx4*)xf;
                    floatx4 v1 = *(const floatx4*)(xf + 4);
                    av[0]=(short)f2bf(v0[0]); av[1]=(short)f2bf(v0[1]);
                    av[2]=(short)f2bf(v0[2]); av[3]=(short)f2bf(v0[3]);
                    av[4]=(short)f2bf(v1[0]); av[5]=(short)f2bf(v1[1]);
                    av[6]=(short)f2bf(v1[2]); av[7]=(short)f2bf(v1[3]);
                }
            }
            a[tt] = av;
        }
#pragma unroll
        for (int t = 0; t < 9; ++t) {
            short8 b = *(const short8*)(Wt + (size_t)(t * 16 + mrow) * K_PAD + k);
            acc[0][t] = __builtin_amdgcn_mfma_f32_16x16x32_bf16(a[0], b, acc[0][t], 0, 0, 0);
            acc[1][t] = __builtin_amdgcn_mfma_f32_16x16x32_bf16(a[1], b, acc[1][t], 0, 0, 0);
        }
    }
#pragma unroll
    for (int tt = 0; tt < 2; ++tt)
#pragma unroll
    for (int t = 0; t < 9; ++t) {
        int n = t * 16 + mrow;                      // C/D col = lane&15
#pragma unroll
        for (int r = 0; r < 4; ++r) {
            int row = m_base + tt * 16 + q * 4 + r; // C/D row = (lane>>4)*4 + reg
            if (row < N_NODES) {
                float v = acc[tt][t][r];
                if (n < 96) hMB[(size_t)row * 96 + n] = f2bf(v);
                else        xLin[(size_t)row * 48 + (n - 96)] =
                                fmaxf(v + ldf(bS, n - 96, isbf), 0.f);
            }
        }
    }
}

// ---------- fused aggregation + MLP: one wave per node ----------
// Register-blocked pair prefetch (64 edges per VMEM) + 4x-unrolled gathers:
// up to 20 independent 16B gathers in flight per wave.
__global__ __launch_bounds__(256)
void k_agg(const u16* __restrict__ hMB, const float* __restrict__ xLin,
           const int* __restrict__ rowptr, const int2* __restrict__ csr_pair,
           const float* __restrict__ dis,
           const float* __restrict__ bMf, const float* __restrict__ bAf,
           const float* __restrict__ W1t, const float* __restrict__ b1f,
           const float* __restrict__ W2f, const float* __restrict__ b2f,
           void* __restrict__ out, const int* __restrict__ flags) {
    __shared__ __align__(16) float hsh[4][F_CAT];
    const int isbf = flags[0];
    const int lane = threadIdx.x & 63;
    const int wave = threadIdx.x >> 6;
    const int node = blockIdx.x * 4 + wave;   // grid = 12500*4 == 50000 exactly

    const int g = lane / 12;                  // edge group 0..5 (g==5: lanes 60-63 pad)
    const int s = lane - g * 12;              // feature slot 0..11 (8 bf16 each)
    const bool active = lane < 60;
    const bool isMax = s < 6;                 // slots 0..5: hM max, 6..11: hA sum

    const int start = rowptr[node];
    const int end   = rowptr[node + 1];
    const float dn  = dis[node];
    const float dn2 = dn * dn;                // self-loop norm

    // self row (bf16), also reused as the pad row
    const u16* nrow = hMB + (size_t)node * 96 + 8 * s;

    // seed with self-loop contribution.
    // max lanes may seed in every group (idempotent under max); SUM lanes
    // seed only in group 0 (else self-loop counted 5x after combine).
    floatx4 a0, a1;
    {
        short8 rv = *(const short8*)nrow;
        float seed = (isMax || g == 0) ? dn2 : 0.f;
#pragma unroll
        for (int j = 0; j < 4; ++j) {
            a0[j] = seed * bf2f((u16)rv[j]);
            a1[j] = seed * bf2f((u16)rv[4 + j]);
        }
    }

    for (int c0 = start; c0 < end; c0 += 64) {
        int cl = end - c0; if (cl > 64) cl = 64;
        // block-load up to 64 pairs: lane i holds edge c0+i  (clamped, no OOB)
        int li = lane < cl ? lane : cl - 1;
        int2 mp = csr_pair[c0 + li];
        float mynm = __int_as_float(mp.y) * dis[mp.x] * dn;   // full norm

        for (int j = 0; j < cl; j += 20) {
            // stage 1: addresses + weights via shfl (no VMEM dependency)
            const u16* rp[4]; float nmv[4]; bool vld[4];
#pragma unroll
            for (int u = 0; u < 4; ++u) {
                int el = j + 5 * u + g;
                bool valid = active && (el < cl);
                int elc = (el < cl) ? el : 0;
                int r    = __shfl(mp.x, elc, 64);
                float nm = __shfl(mynm, elc, 64);
                if (!valid) { nm = isMax ? dn2 : 0.f; }
                rp[u]  = valid ? (hMB + (size_t)r * 96 + 8 * s) : nrow;
                nmv[u] = nm;
                vld[u] = valid;
            }
            // stage 2: 4 independent gathers in flight
            short8 rv[4];
#pragma unroll
            for (int u = 0; u < 4; ++u) rv[u] = *(const short8*)rp[u];
            // stage 3: convert + accumulate
#pragma unroll
            for (int u = 0; u < 4; ++u) {
                floatx4 m0, m1;
#pragma unroll
                for (int jj = 0; jj < 4; ++jj) {
                    m0[jj] = nmv[u] * bf2f((u16)rv[u][jj]);
                    m1[jj] = nmv[u] * bf2f((u16)rv[u][4 + jj]);
                }
                if (isMax) { a0 = max4(a0, m0); a1 = max4(a1, m1); }
                else       { a0 += m0;          a1 += m1; }
            }
        }
    }

    // combine the 5 groups into lanes 0..11
#pragma unroll
    for (int gg = 1; gg < 5; ++gg) {
        int src = lane + 12 * gg;
        floatx4 t0, t1;
#pragma unroll
        for (int j = 0; j < 4; ++j) {
            t0[j] = __shfl(a0[j], src, 64);
            t1[j] = __shfl(a1[j], src, 64);
        }
        if (lane < 12) {
            if (isMax) { a0 = max4(a0, t0); a1 = max4(a1, t1); }
            else       { a0 += t0;          a1 += t1; }
        }
    }

    if (lane < 12) {
        const float* bp = isMax ? (bMf + 8 * lane) : (bAf + 8 * lane - 48);
        floatx4 r0, r1;
#pragma unroll
        for (int j = 0; j < 4; ++j) {
            r0[j] = fmaxf(a0[j] + bp[j],     0.f);
            r1[j] = fmaxf(a1[j] + bp[4 + j], 0.f);
        }
        *(floatx4*)(&hsh[wave][8 * lane])     = r0;
        *(floatx4*)(&hsh[wave][8 * lane + 4]) = r1;
    } else if (lane < 18) {
        const float* xr = xLin + (size_t)node * 48 + 8 * (lane - 12);
        *(floatx4*)(&hsh[wave][96 + 8 * (lane - 12)])     = *(const floatx4*)xr;
        *(floatx4*)(&hsh[wave][96 + 8 * (lane - 12) + 4]) = *(const floatx4*)(xr + 4);
    }
    __syncthreads();

    // MLP: lane j computes mid[j]; W1t[j][k] fp32, float4 loads
    float mid = b1f[lane];
    const float* wrow = W1t + (size_t)lane * F_CAT;
    for (int k = 0; k < F_CAT; k += 4) {
        floatx4 h  = *(const floatx4*)(&hsh[wave][k]);
        floatx4 ww = *(const floatx4*)(wrow + k);
        mid = fmaf(h[0], ww[0], mid);
        mid = fmaf(h[1], ww[1], mid);
        mid = fmaf(h[2], ww[2], mid);
        mid = fmaf(h[3], ww[3], mid);
    }
    mid = fmaxf(mid, 0.f);
    float c2 = mid * W2f[lane];
#pragma unroll
    for (int off = 32; off > 0; off >>= 1) c2 += __shfl_down(c2, off, 64);
    if (lane == 0) {
        float res = c2 + b2f[0];
        if (isbf) ((u16*)out)[node] = f2bf(res);
        else      ((float*)out)[node] = res;
    }
}

extern "C" void kernel_launch(void* const* d_in, const int* in_sizes, int n_in,
                              void* d_out, int out_size, void* d_ws, size_t ws_size,
                              hipStream_t stream) {
    const void* x  = d_in[0];
    const int*  ei = (const int*)d_in[1];
    const void* ew = d_in[2];
    const void* WM = d_in[3];
    const void* bM = d_in[4];
    const void* WA = d_in[5];
    const void* bA = d_in[6];
    const void* WS = d_in[7];
    const void* bS = d_in[8];
    const void* W1 = d_in[9];
    const void* b1 = d_in[10];
    const void* W2 = d_in[11];
    const void* b2 = d_in[12];

    char* p = (char*)d_ws;
    auto alloc = [&](size_t bytes) -> char* {
        char* r = p; p += (bytes + 255) & ~(size_t)255; return r;
    };
    int*   flags    = (int*)  alloc(16);
    float* dis      = (float*)alloc((size_t)N_NODES * 4);
    int*   count    = (int*)  alloc((size_t)N_NODES * 4);
    int*   rowptr   = (int*)  alloc((size_t)(N_NODES + 1) * 4);
    int*   rank     = (int*)  alloc((size_t)N_EDGES * 4);
    int2*  csr_pair = (int2*) alloc((size_t)N_EDGES * 8);
    u16*   hMB      = (u16*)  alloc((size_t)N_NODES * 96 * 2);
    float* xLin     = (float*)alloc((size_t)N_NODES * 48 * 4);
    u16*   Wt       = (u16*)  alloc((size_t)F_CAT * K_PAD * 2);
    float* W1t      = (float*)alloc((size_t)F_CAT * F_MID * 4);
    float* bMf      = (float*)alloc(48 * 4);
    float* bAf      = (float*)alloc(48 * 4);
    float* b1f      = (float*)alloc(64 * 4);
    float* W2f      = (float*)alloc(64 * 4);
    float* b2f      = (float*)alloc(4);

    k_probe <<<1, 64, 0, stream>>>((const u16*)x, ei, flags);
    k_prep  <<<(F_CAT * K_PAD + F_CAT * F_MID + 225 + 255) / 256, 256, 0, stream>>>(
                 WM, WA, WS, W1, bM, bA, b1, W2, b2,
                 Wt, W1t, bMf, bAf, b1f, W2f, b2f, flags);
    hipMemsetAsync(count, 0, (size_t)N_NODES * 4, stream);
    k_epass1<<<(N_EDGES + 255) / 256, 256, 0, stream>>>(ei, count, rank, flags);
    k_scan  <<<1, 1024, 0, stream>>>(count, rowptr);
    k_epass2<<<(N_EDGES + 255) / 256, 256, 0, stream>>>(ei, ew, rowptr, rank, csr_pair, flags);
    k_deg   <<<(N_NODES + 3) / 4, 256, 0, stream>>>(rowptr, csr_pair, dis);
    k_gemm  <<<(N_NODES + 127) / 128, 256, 0, stream>>>(x, Wt, hMB, xLin, bS, flags);
    k_agg   <<<N_NODES / 4, 256, 0, stream>>>(hMB, xLin, rowptr, csr_pair, dis,
                                              bMf, bAf, W1t, b1f, W2f, b2f, d_out, flags);
    (void)in_sizes; (void)n_in; (void)out_size; (void)ws_size;
}

// Round 7
// 347.593 us; speedup vs baseline: 2.1374x; 1.2503x over previous
//
#include <hip/hip_runtime.h>
#include <stdint.h>

#define N_NODES 50000
#define N_EDGES 1600000
#define F_IN    264
#define F_HID   48
#define F_CAT   144
#define F_MID   64
#define K_PAD   288   // 264 padded up to multiple of 32
#define K_MLP   160   // 144 padded up to multiple of 32

typedef unsigned short u16;
typedef unsigned int   u32;

using short8  = __attribute__((ext_vector_type(8))) short;
using floatx4 = __attribute__((ext_vector_type(4))) float;

__device__ __forceinline__ float bf2f(u16 u) {
    return __uint_as_float(((u32)u) << 16);
}
__device__ __forceinline__ u16 f2bf(float f) {
    u32 u = __float_as_uint(f);
    u32 r = (u + 0x7fffu + ((u >> 16) & 1u)) >> 16;   // round-nearest-even
    return (u16)r;
}
// dtype-agnostic scalar float load: isbf ? bf16[i] : f32[i]
__device__ __forceinline__ float ldf(const void* p, size_t i, int isbf) {
    return isbf ? bf2f(((const u16*)p)[i]) : ((const float*)p)[i];
}
__device__ __forceinline__ floatx4 max4(floatx4 a, floatx4 b) {
    floatx4 r;
    r[0] = fmaxf(a[0], b[0]); r[1] = fmaxf(a[1], b[1]);
    r[2] = fmaxf(a[2], b[2]); r[3] = fmaxf(a[3], b[3]);
    return r;
}

// ---------- dtype probe: flags[0]=floats-are-bf16, flags[1]=ints-are-int64 ----
__global__ __launch_bounds__(64)
void k_probe(const u16* __restrict__ xu, const int* __restrict__ ei,
             int* __restrict__ flags) {
    int lane = threadIdx.x;
    u16 h = xu[2 * lane];
    u32 E = (h >> 7) & 0xFF;
    int sane = (h == 0) || (E >= 90 && E <= 140);
    unsigned long long m = __ballot(sane);
    int cnt = __popcll(m);
    int z = (lane < 16) ? ei[2 * lane + 1] : 0;
    unsigned long long nz = __ballot(z != 0);
    if (lane == 0) {
        flags[0] = (cnt >= 48) ? 1 : 0;
        flags[1] = (nz == 0ull) ? 1 : 0;
    }
}

__device__ __forceinline__ int ld_row(const int* ei, int e, int is64) {
    return is64 ? ei[2 * (size_t)e] : ei[e];
}
__device__ __forceinline__ int ld_col(const int* ei, int e, int is64) {
    return is64 ? ei[2 * ((size_t)N_EDGES + e)] : ei[(size_t)N_EDGES + e];
}

// ---------- prep: Wt + W1bt bf16 staging + fp32 conversion of small params ---
__global__ __launch_bounds__(256)
void k_prep(const void* __restrict__ WM, const void* __restrict__ WA,
            const void* __restrict__ WS, const void* __restrict__ W1,
            const void* __restrict__ bM, const void* __restrict__ bA,
            const void* __restrict__ b1, const void* __restrict__ W2,
            const void* __restrict__ b2,
            u16* __restrict__ Wt, u16* __restrict__ W1bt,
            float* __restrict__ bMf, float* __restrict__ bAf,
            float* __restrict__ b1f, float* __restrict__ W2f,
            float* __restrict__ b2f, const int* __restrict__ flags) {
    const int isbf = flags[0];
    int t = blockIdx.x * 256 + threadIdx.x;
    if (t < F_CAT * K_PAD) {
        int n = t / K_PAD, k = t - n * K_PAD;
        u16 v = 0;
        if (k < F_IN) {
            const void* W = (n < 48) ? WM : (n < 96) ? WA : WS;
            int nn = (n < 48) ? n : (n < 96) ? n - 48 : n - 96;
            if (isbf) v = ((const u16*)W)[(size_t)k * 48 + nn];
            else      v = f2bf(((const float*)W)[(size_t)k * 48 + nn]);
        }
        Wt[(size_t)n * K_PAD + k] = v;
        return;
    }
    t -= F_CAT * K_PAD;
    if (t < F_MID * K_MLP) {       // W1bt[j][k] = bf16(W1[k][j]), zero-pad k>=144
        int j = t / K_MLP, k = t - j * K_MLP;
        u16 v = 0;
        if (k < F_CAT) {
            if (isbf) v = ((const u16*)W1)[(size_t)k * F_MID + j];
            else      v = f2bf(((const float*)W1)[(size_t)k * F_MID + j]);
        }
        W1bt[t] = v;
        return;
    }
    t -= F_MID * K_MLP;
    if (t < 48)            { bMf[t] = ldf(bM, t, isbf); return; }
    t -= 48;
    if (t < 48)            { bAf[t] = ldf(bA, t, isbf); return; }
    t -= 48;
    if (t < 64)            { b1f[t] = ldf(b1, t, isbf); return; }
    t -= 64;
    if (t < 64)            { W2f[t] = ldf(W2, t, isbf); return; }
    t -= 64;
    if (t < 1)             { b2f[0] = ldf(b2, 0, isbf); return; }
}

// pass 1: per-edge within-column rank + column counts (the ONLY atomic pass)
__global__ __launch_bounds__(256)
void k_epass1(const int* __restrict__ ei, int* __restrict__ count,
              int* __restrict__ rank, const int* __restrict__ flags) {
    const int is64 = flags[1];
    int e = blockIdx.x * 256 + threadIdx.x;
    if (e >= N_EDGES) return;
    int c = ld_col(ei, e, is64);
    rank[e] = atomicAdd(&count[c], 1);
}

__global__ __launch_bounds__(1024)
void k_scan(const int* __restrict__ count, int* __restrict__ rowptr) {
    __shared__ int part[1024];
    const int tid = threadIdx.x;
    const int CH = 52;                 // 1024*52 = 53248 >= 50000, CH%4==0
    int base = tid * CH;
    int s = 0;
#pragma unroll
    for (int i = 0; i < CH / 4; ++i) {
        int idx = base + 4 * i;
        if (idx < N_NODES) {           // N_NODES%4==0 -> full int4 in bounds
            int4 v = *(const int4*)(count + idx);
            s += v.x + v.y + v.z + v.w;
        }
    }
    part[tid] = s;
    __syncthreads();
    for (int off = 1; off < 1024; off <<= 1) {
        int v = (tid >= off) ? part[tid - off] : 0;
        __syncthreads();
        part[tid] += v;
        __syncthreads();
    }
    int run = part[tid] - s;           // exclusive prefix of this chunk
#pragma unroll
    for (int i = 0; i < CH / 4; ++i) {
        int idx = base + 4 * i;
        if (idx < N_NODES) {
            int4 v = *(const int4*)(count + idx);
            int4 rp;
            rp.x = run; run += v.x;
            rp.y = run; run += v.y;
            rp.z = run; run += v.z;
            rp.w = run; run += v.w;
            *(int4*)(rowptr + idx) = rp;
        }
    }
    if (tid == 1023) rowptr[N_NODES] = part[1023];
}

// pass 2: atomic-free placement — one scattered 8B store per edge (raw w)
__global__ __launch_bounds__(256)
void k_epass2(const int* __restrict__ ei, const void* __restrict__ ew,
              const int* __restrict__ rowptr, const int* __restrict__ rank,
              int2* __restrict__ csr_pair, const int* __restrict__ flags) {
    const int isbf = flags[0], is64 = flags[1];
    int e = blockIdx.x * 256 + threadIdx.x;
    if (e >= N_EDGES) return;
    int r = ld_row(ei, e, is64);
    int c = ld_col(ei, e, is64);
    float w = ldf(ew, e, isbf);
    int p = rowptr[c] + rank[e];
    csr_pair[p] = make_int2(r, __float_as_int(w));
}

// deg/dis from CSR segments, no atomics: one wave per node
__global__ __launch_bounds__(256)
void k_deg(const int* __restrict__ rowptr, const int2* __restrict__ csr_pair,
           float* __restrict__ dis) {
    const int lane = threadIdx.x & 63;
    const int node = blockIdx.x * 4 + (threadIdx.x >> 6);
    int start = rowptr[node], end = rowptr[node + 1];
    float s = 0.f;
    for (int i = start + lane; i < end; i += 64)
        s += __int_as_float(csr_pair[i].y);
#pragma unroll
    for (int off = 32; off > 0; off >>= 1) s += __shfl_down(s, off, 64);
    if (lane == 0) dis[node] = rsqrtf(1.0f + s);   // +1 = self-loop
}

// ---------- GEMM: H[50000 x 144] = x @ [WM|WA|WS] via bf16 MFMA ----------
// hMB[node][96] bf16 (gather table); hFull[node][96..143] = relu(xWS+bS) bf16
__global__ __launch_bounds__(256)
void k_gemm(const void* __restrict__ x, const u16* __restrict__ Wt,
            u16* __restrict__ hMB, u16* __restrict__ hFull,
            const void* __restrict__ bS, const int* __restrict__ flags) {
    const int isbf = flags[0];
    const int lane = threadIdx.x & 63;
    const int wave = threadIdx.x >> 6;
    const int mrow = lane & 15;
    const int q    = lane >> 4;
    const int m_base = blockIdx.x * 128 + wave * 32;

    floatx4 acc[2][9];
#pragma unroll
    for (int tt = 0; tt < 2; ++tt)
#pragma unroll
        for (int t = 0; t < 9; ++t) {
            acc[tt][t][0]=0.f; acc[tt][t][1]=0.f; acc[tt][t][2]=0.f; acc[tt][t][3]=0.f;
        }

    for (int k0 = 0; k0 < K_PAD; k0 += 32) {
        int k = k0 + q * 8;
        short8 a[2];
#pragma unroll
        for (int tt = 0; tt < 2; ++tt) {
            int node = m_base + tt * 16 + mrow;
            short8 av = {0,0,0,0,0,0,0,0};
            if (node < N_NODES && k < F_IN) {
                if (isbf) {
                    av = *(const short8*)((const u16*)x + (size_t)node * F_IN + k);
                } else {
                    const float* xf = (const float*)x + (size_t)node * F_IN + k;
                    floatx4 v0 = *(const floatx4*)xf;
                    floatx4 v1 = *(const floatx4*)(xf + 4);
                    av[0]=(short)f2bf(v0[0]); av[1]=(short)f2bf(v0[1]);
                    av[2]=(short)f2bf(v0[2]); av[3]=(short)f2bf(v0[3]);
                    av[4]=(short)f2bf(v1[0]); av[5]=(short)f2bf(v1[1]);
                    av[6]=(short)f2bf(v1[2]); av[7]=(short)f2bf(v1[3]);
                }
            }
            a[tt] = av;
        }
#pragma unroll
        for (int t = 0; t < 9; ++t) {
            short8 b = *(const short8*)(Wt + (size_t)(t * 16 + mrow) * K_PAD + k);
            acc[0][t] = __builtin_amdgcn_mfma_f32_16x16x32_bf16(a[0], b, acc[0][t], 0, 0, 0);
            acc[1][t] = __builtin_amdgcn_mfma_f32_16x16x32_bf16(a[1], b, acc[1][t], 0, 0, 0);
        }
    }
#pragma unroll
    for (int tt = 0; tt < 2; ++tt)
#pragma unroll
    for (int t = 0; t < 9; ++t) {
        int n = t * 16 + mrow;                      // C/D col = lane&15
#pragma unroll
        for (int r = 0; r < 4; ++r) {
            int row = m_base + tt * 16 + q * 4 + r; // C/D row = (lane>>4)*4 + reg
            if (row < N_NODES) {
                float v = acc[tt][t][r];
                if (n < 96) hMB[(size_t)row * 96 + n] = f2bf(v);
                else        hFull[(size_t)row * F_CAT + n] =
                                f2bf(fmaxf(v + ldf(bS, n - 96, isbf), 0.f));
            }
        }
    }
}

// ---------- aggregation only: one wave per node, writes hFull[.][0..95] ------
// Register-blocked pair prefetch (64 edges per VMEM) + 4x-unrolled gathers.
// No LDS, no syncthreads, no MLP (that moved to k_mlp).
__global__ __launch_bounds__(256)
void k_agg(const u16* __restrict__ hMB, u16* __restrict__ hFull,
           const int* __restrict__ rowptr, const int2* __restrict__ csr_pair,
           const float* __restrict__ dis,
           const float* __restrict__ bMf, const float* __restrict__ bAf) {
    const int lane = threadIdx.x & 63;
    const int wave = threadIdx.x >> 6;
    const int node = blockIdx.x * 4 + wave;   // grid = 12500*4 == 50000 exactly

    const int g = lane / 12;                  // edge group 0..5 (g==5: lanes 60-63 pad)
    const int s = lane - g * 12;              // feature slot 0..11 (8 bf16 each)
    const bool active = lane < 60;
    const bool isMax = s < 6;                 // slots 0..5: hM max, 6..11: hA sum

    const int start = rowptr[node];
    const int end   = rowptr[node + 1];
    const float dn  = dis[node];
    const float dn2 = dn * dn;                // self-loop norm

    // self row (bf16), also reused as the pad row
    const u16* nrow = hMB + (size_t)node * 96 + 8 * s;

    // seed with self-loop contribution.
    // max lanes may seed in every group (idempotent under max); SUM lanes
    // seed only in group 0 (else self-loop counted 5x after combine).
    floatx4 a0, a1;
    {
        short8 rv = *(const short8*)nrow;
        float seed = (isMax || g == 0) ? dn2 : 0.f;
#pragma unroll
        for (int j = 0; j < 4; ++j) {
            a0[j] = seed * bf2f((u16)rv[j]);
            a1[j] = seed * bf2f((u16)rv[4 + j]);
        }
    }

    for (int c0 = start; c0 < end; c0 += 64) {
        int cl = end - c0; if (cl > 64) cl = 64;
        // block-load up to 64 pairs: lane i holds edge c0+i  (clamped, no OOB)
        int li = lane < cl ? lane : cl - 1;
        int2 mp = csr_pair[c0 + li];
        float mynm = __int_as_float(mp.y) * dis[mp.x] * dn;   // full norm

        for (int j = 0; j < cl; j += 20) {
            // stage 1: addresses + weights via shfl (no VMEM dependency)
            const u16* rp[4]; float nmv[4];
#pragma unroll
            for (int u = 0; u < 4; ++u) {
                int el = j + 5 * u + g;
                bool valid = active && (el < cl);
                int elc = (el < cl) ? el : 0;
                int r    = __shfl(mp.x, elc, 64);
                float nm = __shfl(mynm, elc, 64);
                if (!valid) { nm = isMax ? dn2 : 0.f; }
                rp[u]  = valid ? (hMB + (size_t)r * 96 + 8 * s) : nrow;
                nmv[u] = nm;
            }
            // stage 2: 4 independent gathers in flight
            short8 rv[4];
#pragma unroll
            for (int u = 0; u < 4; ++u) rv[u] = *(const short8*)rp[u];
            // stage 3: convert + accumulate
#pragma unroll
            for (int u = 0; u < 4; ++u) {
                floatx4 m0, m1;
#pragma unroll
                for (int jj = 0; jj < 4; ++jj) {
                    m0[jj] = nmv[u] * bf2f((u16)rv[u][jj]);
                    m1[jj] = nmv[u] * bf2f((u16)rv[u][4 + jj]);
                }
                if (isMax) { a0 = max4(a0, m0); a1 = max4(a1, m1); }
                else       { a0 += m0;          a1 += m1; }
            }
        }
    }

    // combine the 5 groups into lanes 0..11
#pragma unroll
    for (int gg = 1; gg < 5; ++gg) {
        int src = lane + 12 * gg;
        floatx4 t0, t1;
#pragma unroll
        for (int j = 0; j < 4; ++j) {
            t0[j] = __shfl(a0[j], src, 64);
            t1[j] = __shfl(a1[j], src, 64);
        }
        if (lane < 12) {
            if (isMax) { a0 = max4(a0, t0); a1 = max4(a1, t1); }
            else       { a0 += t0;          a1 += t1; }
        }
    }

    if (lane < 12) {
        const float* bp = isMax ? (bMf + 8 * lane) : (bAf + 8 * lane - 48);
        short8 hv;
#pragma unroll
        for (int j = 0; j < 4; ++j) {
            hv[j]     = (short)f2bf(fmaxf(a0[j] + bp[j],     0.f));
            hv[4 + j] = (short)f2bf(fmaxf(a1[j] + bp[4 + j], 0.f));
        }
        *(short8*)(hFull + (size_t)node * F_CAT + 8 * lane) = hv;
    }
}

// ---------- MLP via MFMA: out = (relu(hFull@W1+b1))@W2 + b2 ----------------
// M=50000, K=144 (pad 160), N=64; fused ReLU + W2 dot + b2 in epilogue.
__global__ __launch_bounds__(256)
void k_mlp(const u16* __restrict__ hFull, const u16* __restrict__ W1bt,
           const float* __restrict__ b1f, const float* __restrict__ W2f,
           const float* __restrict__ b2f, void* __restrict__ out,
           const int* __restrict__ flags) {
    const int isbf = flags[0];
    const int lane = threadIdx.x & 63;
    const int wave = threadIdx.x >> 6;
    const int mrow = lane & 15;
    const int q    = lane >> 4;
    const int m_base = blockIdx.x * 64 + wave * 16;
    const int node = m_base + mrow;           // A-operand row

    floatx4 acc[4];
#pragma unroll
    for (int t = 0; t < 4; ++t) { acc[t][0]=0.f; acc[t][1]=0.f; acc[t][2]=0.f; acc[t][3]=0.f; }

    for (int k0 = 0; k0 < K_MLP; k0 += 32) {
        int k = k0 + q * 8;
        short8 a = {0,0,0,0,0,0,0,0};
        if (node < N_NODES && k < F_CAT)
            a = *(const short8*)(hFull + (size_t)node * F_CAT + k);
#pragma unroll
        for (int t = 0; t < 4; ++t) {
            short8 b = *(const short8*)(W1bt + (size_t)(t * 16 + mrow) * K_MLP + k);
            acc[t] = __builtin_amdgcn_mfma_f32_16x16x32_bf16(a, b, acc[t], 0, 0, 0);
        }
    }

    // epilogue: per lane col c=mrow holds mid[n=t*16+c] for rows m=q*4+r
    float pr[4] = {0.f, 0.f, 0.f, 0.f};
#pragma unroll
    for (int t = 0; t < 4; ++t) {
        int n = t * 16 + mrow;
        float b1v = b1f[n], w2v = W2f[n];
#pragma unroll
        for (int r = 0; r < 4; ++r)
            pr[r] += fmaxf(acc[t][r] + b1v, 0.f) * w2v;
    }
    // reduce across the 16 columns (lanes with equal q)
#pragma unroll
    for (int mask = 1; mask < 16; mask <<= 1)
#pragma unroll
        for (int r = 0; r < 4; ++r) pr[r] += __shfl_xor(pr[r], mask, 64);
    if (mrow == 0) {
#pragma unroll
        for (int r = 0; r < 4; ++r) {
            int nd = m_base + q * 4 + r;
            if (nd < N_NODES) {
                float res = pr[r] + b2f[0];
                if (isbf) ((u16*)out)[nd] = f2bf(res);
                else      ((float*)out)[nd] = res;
            }
        }
    }
}

extern "C" void kernel_launch(void* const* d_in, const int* in_sizes, int n_in,
                              void* d_out, int out_size, void* d_ws, size_t ws_size,
                              hipStream_t stream) {
    const void* x  = d_in[0];
    const int*  ei = (const int*)d_in[1];
    const void* ew = d_in[2];
    const void* WM = d_in[3];
    const void* bM = d_in[4];
    const void* WA = d_in[5];
    const void* bA = d_in[6];
    const void* WS = d_in[7];
    const void* bS = d_in[8];
    const void* W1 = d_in[9];
    const void* b1 = d_in[10];
    const void* W2 = d_in[11];
    const void* b2 = d_in[12];

    char* p = (char*)d_ws;
    auto alloc = [&](size_t bytes) -> char* {
        char* r = p; p += (bytes + 255) & ~(size_t)255; return r;
    };
    int*   flags    = (int*)  alloc(16);
    float* dis      = (float*)alloc((size_t)N_NODES * 4);
    int*   count    = (int*)  alloc((size_t)N_NODES * 4);
    int*   rowptr   = (int*)  alloc((size_t)(N_NODES + 1) * 4);
    int*   rank     = (int*)  alloc((size_t)N_EDGES * 4);
    int2*  csr_pair = (int2*) alloc((size_t)N_EDGES * 8);
    u16*   hMB      = (u16*)  alloc((size_t)N_NODES * 96 * 2);
    u16*   hFull    = (u16*)  alloc((size_t)N_NODES * F_CAT * 2);
    u16*   Wt       = (u16*)  alloc((size_t)F_CAT * K_PAD * 2);
    u16*   W1bt     = (u16*)  alloc((size_t)F_MID * K_MLP * 2);
    float* bMf      = (float*)alloc(48 * 4);
    float* bAf      = (float*)alloc(48 * 4);
    float* b1f      = (float*)alloc(64 * 4);
    float* W2f      = (float*)alloc(64 * 4);
    float* b2f      = (float*)alloc(4);

    k_probe <<<1, 64, 0, stream>>>((const u16*)x, ei, flags);
    k_prep  <<<(F_CAT * K_PAD + F_MID * K_MLP + 225 + 255) / 256, 256, 0, stream>>>(
                 WM, WA, WS, W1, bM, bA, b1, W2, b2,
                 Wt, W1bt, bMf, bAf, b1f, W2f, b2f, flags);
    hipMemsetAsync(count, 0, (size_t)N_NODES * 4, stream);
    k_epass1<<<(N_EDGES + 255) / 256, 256, 0, stream>>>(ei, count, rank, flags);
    k_scan  <<<1, 1024, 0, stream>>>(count, rowptr);
    k_epass2<<<(N_EDGES + 255) / 256, 256, 0, stream>>>(ei, ew, rowptr, rank, csr_pair, flags);
    k_deg   <<<(N_NODES + 3) / 4, 256, 0, stream>>>(rowptr, csr_pair, dis);
    k_gemm  <<<(N_NODES + 127) / 128, 256, 0, stream>>>(x, Wt, hMB, hFull, bS, flags);
    k_agg   <<<N_NODES / 4, 256, 0, stream>>>(hMB, hFull, rowptr, csr_pair, dis, bMf, bAf);
    k_mlp   <<<(N_NODES + 63) / 64, 256, 0, stream>>>(hFull, W1bt, b1f, W2f, b2f, d_out, flags);
    (void)in_sizes; (void)n_in; (void)out_size; (void)ws_size;
}